// Round 2
// baseline (572.927 us; speedup 1.0000x reference)
//
#include <hip/hip_runtime.h>

// ResidualLogitAdapter: out = z + scatter_add(dz into domain window)
// dz = relu([feats, conf_stats(z_window)] @ W1 + b1) @ W2 + b2, * alpha[dom]
// N=131072, G=512, F=256, H=128, K=64, D=8

typedef __attribute__((ext_vector_type(8))) short short8;
typedef __attribute__((ext_vector_type(4))) float f32x4;

#define NROWS_TOT 131072
#define G 512
#define F 256
#define HID 128
#define KW 64
#define MROWS 16
#define XROW 296   // bf16 row stride in LDS: 148 dwords, 148%32=20 -> ~2-way banks (free)
#define HROW 136   // 68 dwords, 68%32=4 -> spread banks
#define W1FRAG_ELEMS (9*8*64*8)   // 36864 bf16 (K padded 259->288)
#define W2FRAG_ELEMS (4*4*64*8)   // 8192 bf16

__device__ __forceinline__ unsigned short f2bf(float f) {
  unsigned u = __float_as_uint(f);
  u += 0x7FFFu + ((u >> 16) & 1u);
  return (unsigned short)(u >> 16);
}

// Swizzle W1/W2 into MFMA B-fragment order:
// B[k][n] for tile (kc,nt): value at lane, j  is  B[kc*32 + (lane>>4)*8 + j][nt*16 + (lane&15)]
// stored flat at ((kc*NT + nt)*64 + lane)*8 + j
__global__ void prep_kernel(const float* __restrict__ W1, const float* __restrict__ W2,
                            unsigned short* __restrict__ ws) {
  int f = blockIdx.x * 256 + threadIdx.x;   // 176*256 = 45056 = 36864 + 8192 exactly
  if (f < W1FRAG_ELEMS) {
    int j = f & 7, lane = (f >> 3) & 63, tile = f >> 9;
    int nt = tile & 7, kc = tile >> 3;
    int k = kc * 32 + ((lane >> 4) << 3) + j;
    int n = (nt << 4) + (lane & 15);
    float v = (k < 259) ? W1[k * HID + n] : 0.0f;
    ws[f] = f2bf(v);
  } else {
    int f2 = f - W1FRAG_ELEMS;
    int j = f2 & 7, lane = (f2 >> 3) & 63, tile = f2 >> 9;
    int nt = tile & 3, kc = tile >> 2;
    int k = kc * 32 + ((lane >> 4) << 3) + j;
    int n = (nt << 4) + (lane & 15);
    ws[W1FRAG_ELEMS + f2] = f2bf(W2[k * KW + n]);
  }
}

// MROWS=16, LDS ~18 KiB. z rows prefetched into 32 VGPRs at kernel start
// (8 independent float4 loads -> deep MLP), carried across GEMMs, fused
// add+store at the end. VGPR ~76 -> 6 blocks/CU (24 waves, 75%).
__global__ __launch_bounds__(256, 6) void adapter_main(
    const float* __restrict__ z, const float* __restrict__ feats,
    const float* __restrict__ b1, const float* __restrict__ b2,
    const float* __restrict__ alphas, const int* __restrict__ dom_ids,
    const unsigned short* __restrict__ wfrag, float* __restrict__ out) {
  __shared__ unsigned short Xb[MROWS * XROW];  // 9472 B
  __shared__ unsigned short Hb[MROWS * HROW];  // 4352 B
  __shared__ float dzs[MROWS * KW];            // 4096 B
  __shared__ float alph[MROWS];
  __shared__ int   doms[MROWS];

  const int tid  = threadIdx.x;
  const int lane = tid & 63;
  const int wv   = tid >> 6;
  const int l15  = lane & 15;
  const int quad = lane >> 4;
  const int r0   = blockIdx.x * MROWS;

  // ---- Phase Z: prefetch full z rows into registers (8-deep MLP) ----
  float4 zr[8];
  #pragma unroll
  for (int it = 0; it < 8; ++it) {
    int flat = it * 256 + tid;       // 16 rows x 128 float4
    int row  = flat >> 7;
    int c4   = flat & 127;
    zr[it] = *(const float4*)&z[(size_t)(r0 + row) * G + c4 * 4];
  }

  // ---- Phase A1: feats -> Xb (bf16), float4 coalesced ----
  {
    int rsub = tid >> 6;     // 0..3
    int c4   = tid & 63;     // 0..63
    #pragma unroll
    for (int i = 0; i < 4; ++i) {
      int row = i * 4 + rsub;
      const float4 v = *(const float4*)&feats[(size_t)(r0 + row) * F + c4 * 4];
      ushort4 p;
      p.x = f2bf(v.x); p.y = f2bf(v.y); p.z = f2bf(v.z); p.w = f2bf(v.w);
      *(ushort4*)&Xb[row * XROW + c4 * 4] = p;
    }
  }

  // ---- Phase A2: conf stats, one wave per row (window reads hit L2: same
  //      lines as Phase Z's prefetch of this block's rows) ----
  #pragma unroll
  for (int row = wv; row < MROWS; row += 4) {
    const int gr = r0 + row;
    const int d  = dom_ids[gr];
    float l = z[(size_t)gr * G + d * KW + lane];
    float m = l;
    #pragma unroll
    for (int off = 32; off; off >>= 1) m = fmaxf(m, __shfl_xor(m, off));
    float e = __expf(l - m);
    float S = e, wsum = e * (l - m);
    #pragma unroll
    for (int off = 32; off; off >>= 1) { S += __shfl_xor(S, off); wsum += __shfl_xor(wsum, off); }
    float l2 = (l < m) ? l : -1e30f;
    #pragma unroll
    for (int off = 32; off; off >>= 1) l2 = fmaxf(l2, __shfl_xor(l2, off));
    float inv    = 1.0f / S;
    float pmax   = inv;                       // exp(0)/S
    float ent    = __logf(S) - wsum * inv;
    float margin = (1.0f - __expf(l2 - m)) * inv;
    if (lane < 40) {  // cols 256..295: stats then zero-pad (K padded to 288)
      float v = (lane == 0) ? pmax : (lane == 1) ? ent : (lane == 2) ? margin : 0.0f;
      Xb[row * XROW + 256 + lane] = f2bf(v);
    }
    if (lane == 0) { doms[row] = d; alph[row] = alphas[d]; }
  }
  __syncthreads();

  // ---- Phase B: trunk GEMM  X[16,288] @ W1[288,128] -> Hb (relu, bf16) ----
  {
    const int ntb = wv * 2;   // 4 waves cover ntiles 0..7, 2 each (single mtile)
    f32x4 acc[2];
    acc[0] = f32x4{0.f, 0.f, 0.f, 0.f};
    acc[1] = f32x4{0.f, 0.f, 0.f, 0.f};
    const unsigned short* Arow = &Xb[l15 * XROW];
    const short8* Wp = (const short8*)wfrag;
    #pragma unroll
    for (int kc = 0; kc < 9; ++kc) {
      short8 a = *(const short8*)&Arow[kc * 32 + quad * 8];
      const short8* bp = Wp + (size_t)(kc * 8 + ntb) * 64 + lane;
      short8 bf0 = bp[0], bf1 = bp[64];
      acc[0] = __builtin_amdgcn_mfma_f32_16x16x32_bf16(a, bf0, acc[0], 0, 0, 0);
      acc[1] = __builtin_amdgcn_mfma_f32_16x16x32_bf16(a, bf1, acc[1], 0, 0, 0);
    }
    #pragma unroll
    for (int t = 0; t < 2; ++t) {
      int n = (ntb + t) * 16 + l15;
      float bias = b1[n];
      #pragma unroll
      for (int r = 0; r < 4; ++r) {
        int row = quad * 4 + r;   // C/D: col=lane&15, row=quad*4+reg
        Hb[row * HROW + n] = f2bf(fmaxf(acc[t][r] + bias, 0.f));
      }
    }
  }
  __syncthreads();

  // ---- Phase C: head GEMM  H[16,128] @ W2[128,64] -> dzs (fp32, *alpha) ----
  {
    const int nt0 = wv;   // 4 waves cover ntiles 0..3, 1 each
    f32x4 acc2 = f32x4{0.f, 0.f, 0.f, 0.f};
    const unsigned short* Arow = &Hb[l15 * HROW];
    const short8* Wp = (const short8*)(wfrag + W1FRAG_ELEMS);
    #pragma unroll
    for (int kc = 0; kc < 4; ++kc) {
      short8 a = *(const short8*)&Arow[kc * 32 + quad * 8];
      const short8* bp = Wp + (kc * 4 + nt0) * 64 + lane;
      acc2 = __builtin_amdgcn_mfma_f32_16x16x32_bf16(a, bp[0], acc2, 0, 0, 0);
    }
    {
      int n = nt0 * 16 + l15;
      float bias = b2[n];
      #pragma unroll
      for (int r = 0; r < 4; ++r) {
        int row = quad * 4 + r;
        dzs[row * KW + n] = (acc2[r] + bias) * alph[row];
      }
    }
  }
  __syncthreads();

  // ---- Phase D: out = zr + dz window (z already in registers) ----
  #pragma unroll
  for (int it = 0; it < 8; ++it) {
    int flat = it * 256 + tid;       // 16 rows x 128 float4
    int row  = flat >> 7;
    int c4   = flat & 127;
    size_t gidx = (size_t)(r0 + row) * G + c4 * 4;
    float4 v = zr[it];
    int off = c4 - doms[row] * 16;
    if ((unsigned)off < 16u) {
      const float4 dv = *(const float4*)&dzs[row * KW + off * 4];
      v.x += dv.x; v.y += dv.y; v.z += dv.z; v.w += dv.w;
    }
    *(float4*)&out[gidx] = v;
  }
}

extern "C" void kernel_launch(void* const* d_in, const int* in_sizes, int n_in,
                              void* d_out, int out_size, void* d_ws, size_t ws_size,
                              hipStream_t stream) {
  const float* z      = (const float*)d_in[0];
  const float* feats  = (const float*)d_in[1];
  const float* W1     = (const float*)d_in[2];
  const float* b1     = (const float*)d_in[3];
  const float* W2     = (const float*)d_in[4];
  const float* b2     = (const float*)d_in[5];
  const float* alphas = (const float*)d_in[6];
  const int*   dom    = (const int*)d_in[7];
  unsigned short* wfrag = (unsigned short*)d_ws;
  float* out = (float*)d_out;

  // ws is re-poisoned before every launch -> rebuild fragments every call.
  hipLaunchKernelGGL(prep_kernel, dim3(176), dim3(256), 0, stream, W1, W2, wfrag);
  hipLaunchKernelGGL(adapter_main, dim3(NROWS_TOT / MROWS), dim3(256), 0, stream,
                     z, feats, b1, b2, alphas, dom, wfrag, out);
}

// Round 3
// 526.118 us; speedup vs baseline: 1.0890x; 1.0890x over previous
//
#include <hip/hip_runtime.h>

// ResidualLogitAdapter: out = z + scatter_add(dz into domain window)
// dz = relu([feats, conf_stats(z_window)] @ W1 + b1) @ W2 + b2, * alpha[dom]
// N=131072, G=512, F=256, H=128, K=64, D=8

typedef __attribute__((ext_vector_type(8))) short short8;
typedef __attribute__((ext_vector_type(4))) float f32x4;

#define NROWS_TOT 131072
#define G 512
#define F 256
#define HID 128
#define KW 64
#define MROWS 16
#define XROW 296   // bf16 row stride in LDS: 148 dwords, 148%32=20 -> ~2-way banks (free)
#define HROW 136   // 68 dwords, 68%32=4 -> spread banks
#define W1FRAG_ELEMS (9*8*64*8)   // 36864 bf16 (K padded 259->288)
#define W2FRAG_ELEMS (4*4*64*8)   // 8192 bf16

__device__ __forceinline__ unsigned short f2bf(float f) {
  unsigned u = __float_as_uint(f);
  u += 0x7FFFu + ((u >> 16) & 1u);
  return (unsigned short)(u >> 16);
}

// Swizzle W1/W2 into MFMA B-fragment order:
// B[k][n] for tile (kc,nt): value at lane, j  is  B[kc*32 + (lane>>4)*8 + j][nt*16 + (lane&15)]
// stored flat at ((kc*NT + nt)*64 + lane)*8 + j
__global__ void prep_kernel(const float* __restrict__ W1, const float* __restrict__ W2,
                            unsigned short* __restrict__ ws) {
  int f = blockIdx.x * 256 + threadIdx.x;   // 176*256 = 45056 = 36864 + 8192 exactly
  if (f < W1FRAG_ELEMS) {
    int j = f & 7, lane = (f >> 3) & 63, tile = f >> 9;
    int nt = tile & 7, kc = tile >> 3;
    int k = kc * 32 + ((lane >> 4) << 3) + j;
    int n = (nt << 4) + (lane & 15);
    float v = (k < 259) ? W1[k * HID + n] : 0.0f;
    ws[f] = f2bf(v);
  } else {
    int f2 = f - W1FRAG_ELEMS;
    int j = f2 & 7, lane = (f2 >> 3) & 63, tile = f2 >> 9;
    int nt = tile & 3, kc = tile >> 2;
    int k = kc * 32 + ((lane >> 4) << 3) + j;
    int n = (nt << 4) + (lane & 15);
    ws[W1FRAG_ELEMS + f2] = f2bf(W2[k * KW + n]);
  }
}

// MROWS=16, LDS ~18 KiB -> 8 blocks/CU (32 waves, 100% cap). All global-load
// batches are issued N-deep WITHIN a phase (no values held across barriers --
// round-2 lesson: cross-barrier float4 arrays spill to scratch, +180 MB HBM).
__global__ __launch_bounds__(256, 8) void adapter_main(
    const float* __restrict__ z, const float* __restrict__ feats,
    const float* __restrict__ b1, const float* __restrict__ b2,
    const float* __restrict__ alphas, const int* __restrict__ dom_ids,
    const unsigned short* __restrict__ wfrag, float* __restrict__ out) {
  __shared__ unsigned short Xb[MROWS * XROW];  // 9472 B
  __shared__ unsigned short Hb[MROWS * HROW];  // 4352 B
  __shared__ float dzs[MROWS * KW];            // 4096 B
  __shared__ float alph[MROWS];
  __shared__ int   doms[MROWS];

  const int tid  = threadIdx.x;
  const int lane = tid & 63;
  const int wv   = tid >> 6;
  const int l15  = lane & 15;
  const int quad = lane >> 4;
  const int r0   = blockIdx.x * MROWS;

  // ---- Phase A1: feats -> Xb (bf16); 4 loads issued before any consume ----
  {
    int rsub = tid >> 6;     // 0..3
    int c4   = tid & 63;     // 0..63
    float4 fv[4];
    #pragma unroll
    for (int i = 0; i < 4; ++i) {
      int row = i * 4 + rsub;
      fv[i] = *(const float4*)&feats[(size_t)(r0 + row) * F + c4 * 4];
    }
    #pragma unroll
    for (int i = 0; i < 4; ++i) {
      int row = i * 4 + rsub;
      ushort4 p;
      p.x = f2bf(fv[i].x); p.y = f2bf(fv[i].y); p.z = f2bf(fv[i].z); p.w = f2bf(fv[i].w);
      *(ushort4*)&Xb[row * XROW + c4 * 4] = p;
    }
  }

  // ---- Phase A2: conf stats; batch the 4 dom loads, then the 4 window
  //      loads, then 4 independent shuffle-reduce chains (interleavable) ----
  {
    int dv[4];
    float lv[4];
    #pragma unroll
    for (int i = 0; i < 4; ++i) dv[i] = dom_ids[r0 + wv + i * 4];
    #pragma unroll
    for (int i = 0; i < 4; ++i) {
      int gr = r0 + wv + i * 4;
      lv[i] = z[(size_t)gr * G + dv[i] * KW + lane];
    }
    #pragma unroll
    for (int i = 0; i < 4; ++i) {
      int row = wv + i * 4;
      float l = lv[i];
      float m = l;
      #pragma unroll
      for (int off = 32; off; off >>= 1) m = fmaxf(m, __shfl_xor(m, off));
      float e = __expf(l - m);
      float S = e, wsum = e * (l - m);
      #pragma unroll
      for (int off = 32; off; off >>= 1) { S += __shfl_xor(S, off); wsum += __shfl_xor(wsum, off); }
      float l2 = (l < m) ? l : -1e30f;
      #pragma unroll
      for (int off = 32; off; off >>= 1) l2 = fmaxf(l2, __shfl_xor(l2, off));
      float inv    = 1.0f / S;
      float pmax   = inv;                       // exp(0)/S
      float ent    = __logf(S) - wsum * inv;
      float margin = (1.0f - __expf(l2 - m)) * inv;
      if (lane < 40) {  // cols 256..295: stats then zero-pad (K padded to 288)
        float v = (lane == 0) ? pmax : (lane == 1) ? ent : (lane == 2) ? margin : 0.0f;
        Xb[row * XROW + 256 + lane] = f2bf(v);
      }
      if (lane == 0) { doms[row] = dv[i]; alph[row] = alphas[dv[i]]; }
    }
  }
  __syncthreads();

  // ---- Phase B: trunk GEMM  X[16,288] @ W1[288,128] -> Hb (relu, bf16) ----
  {
    const int ntb = wv * 2;   // 4 waves cover ntiles 0..7, 2 each (single mtile)
    f32x4 acc[2];
    acc[0] = f32x4{0.f, 0.f, 0.f, 0.f};
    acc[1] = f32x4{0.f, 0.f, 0.f, 0.f};
    const unsigned short* Arow = &Xb[l15 * XROW];
    const short8* Wp = (const short8*)wfrag;
    #pragma unroll
    for (int kc = 0; kc < 9; ++kc) {
      short8 a = *(const short8*)&Arow[kc * 32 + quad * 8];
      const short8* bp = Wp + (size_t)(kc * 8 + ntb) * 64 + lane;
      short8 bf0 = bp[0], bf1 = bp[64];
      acc[0] = __builtin_amdgcn_mfma_f32_16x16x32_bf16(a, bf0, acc[0], 0, 0, 0);
      acc[1] = __builtin_amdgcn_mfma_f32_16x16x32_bf16(a, bf1, acc[1], 0, 0, 0);
    }
    #pragma unroll
    for (int t = 0; t < 2; ++t) {
      int n = (ntb + t) * 16 + l15;
      float bias = b1[n];
      #pragma unroll
      for (int r = 0; r < 4; ++r) {
        int row = quad * 4 + r;   // C/D: col=lane&15, row=quad*4+reg
        Hb[row * HROW + n] = f2bf(fmaxf(acc[t][r] + bias, 0.f));
      }
    }
  }
  __syncthreads();

  // ---- Phase C: head GEMM  H[16,128] @ W2[128,64] -> dzs (fp32, *alpha) ----
  {
    const int nt0 = wv;   // 4 waves cover ntiles 0..3, 1 each
    f32x4 acc2 = f32x4{0.f, 0.f, 0.f, 0.f};
    const unsigned short* Arow = &Hb[l15 * HROW];
    const short8* Wp = (const short8*)(wfrag + W1FRAG_ELEMS);
    #pragma unroll
    for (int kc = 0; kc < 4; ++kc) {
      short8 a = *(const short8*)&Arow[kc * 32 + quad * 8];
      const short8* bp = Wp + (kc * 4 + nt0) * 64 + lane;
      acc2 = __builtin_amdgcn_mfma_f32_16x16x32_bf16(a, bp[0], acc2, 0, 0, 0);
    }
    {
      int n = nt0 * 16 + l15;
      float bias = b2[n];
      #pragma unroll
      for (int r = 0; r < 4; ++r) {
        int row = quad * 4 + r;
        dzs[row * KW + n] = (acc2[r] + bias) * alph[row];
      }
    }
  }
  __syncthreads();

  // ---- Phase D: 8 z-loads issued back-to-back (8-deep MLP, lifetime only
  //      within this phase), then add dz window + store ----
  {
    float4 zv[8];
    #pragma unroll
    for (int it = 0; it < 8; ++it) {
      int flat = it * 256 + tid;     // 16 rows x 128 float4
      int row  = flat >> 7;
      int c4   = flat & 127;
      zv[it] = *(const float4*)&z[(size_t)(r0 + row) * G + c4 * 4];
    }
    #pragma unroll
    for (int it = 0; it < 8; ++it) {
      int flat = it * 256 + tid;
      int row  = flat >> 7;
      int c4   = flat & 127;
      size_t gidx = (size_t)(r0 + row) * G + c4 * 4;
      float4 v = zv[it];
      int off = c4 - doms[row] * 16;
      if ((unsigned)off < 16u) {
        const float4 dv = *(const float4*)&dzs[row * KW + off * 4];
        v.x += dv.x; v.y += dv.y; v.z += dv.z; v.w += dv.w;
      }
      *(float4*)&out[gidx] = v;
    }
  }
}

extern "C" void kernel_launch(void* const* d_in, const int* in_sizes, int n_in,
                              void* d_out, int out_size, void* d_ws, size_t ws_size,
                              hipStream_t stream) {
  const float* z      = (const float*)d_in[0];
  const float* feats  = (const float*)d_in[1];
  const float* W1     = (const float*)d_in[2];
  const float* b1     = (const float*)d_in[3];
  const float* W2     = (const float*)d_in[4];
  const float* b2     = (const float*)d_in[5];
  const float* alphas = (const float*)d_in[6];
  const int*   dom    = (const int*)d_in[7];
  unsigned short* wfrag = (unsigned short*)d_ws;
  float* out = (float*)d_out;

  // ws is re-poisoned before every launch -> rebuild fragments every call.
  hipLaunchKernelGGL(prep_kernel, dim3(176), dim3(256), 0, stream, W1, W2, wfrag);
  hipLaunchKernelGGL(adapter_main, dim3(NROWS_TOT / MROWS), dim3(256), 0, stream,
                     z, feats, b1, b2, alphas, dom, wfrag, out);
}